// Round 5
// baseline (276.859 us; speedup 1.0000x reference)
//
#include <hip/hip_runtime.h>

// ProtoSAE fused: h = relu(BN(x@W1^T + b1)); enc = h@W2^T + b2; act = f(||enc-proto||^2)
// T=8192, NI=1024, L=128, H=128, P=64.
// R5: i8 GEMM1 (per-row symmetric quant, i32 accum) on 128-tok x 256-hcol (2 latents)
//     blocks, 8 waves, single-buffered 48 KB LDS, proven 0-conflict swizzle.
//     Epilogue constants folded; quant prepasses merged.

#define NTOK 8192
#define NI   1024
#define NL   128
#define NH   128
#define NP   64

typedef __bf16 bf16x8 __attribute__((ext_vector_type(8)));
typedef float f32x4 __attribute__((ext_vector_type(4)));
typedef int   i32x4 __attribute__((ext_vector_type(4)));

static __device__ __forceinline__ unsigned short f2bf(float f) {
  union { float f; unsigned int u; } v; v.f = f;
  const unsigned int u = v.u;
  return (unsigned short)((u + 0x7fffu + ((u >> 16) & 1u)) >> 16);  // RNE
}

// W2 -> bf16 (8 elems/thread)
__global__ void cvt_f32_bf16(const float* __restrict__ in,
                             unsigned short* __restrict__ out, int n8) {
  const int i = blockIdx.x * blockDim.x + threadIdx.x;
  if (i >= n8) return;
  const float4* p = (const float4*)in;
  const float4 a = p[2 * i], b = p[2 * i + 1];
  unsigned short v[8] __attribute__((aligned(16))) = {
      f2bf(a.x), f2bf(a.y), f2bf(a.z), f2bf(a.w),
      f2bf(b.x), f2bf(b.y), f2bf(b.z), f2bf(b.w)};
  ((uint4*)out)[i] = *(const uint4*)v;
}

// per-row symmetric int8 quantization of x (rows<NTOK) and W1 (rest); 1 wave per row
__global__ void quant_rows_i8_dual(const float* __restrict__ x,
                                   const float* __restrict__ w1,
                                   signed char* __restrict__ xq,
                                   signed char* __restrict__ w1q,
                                   float* __restrict__ sx,
                                   float* __restrict__ sw) {
  const int row = blockIdx.x * 4 + (threadIdx.x >> 6);
  const int lane = threadIdx.x & 63;
  const float* src;
  unsigned int* dst;
  float* sp;
  if (row < NTOK) {
    src = x + (size_t)row * 1024;
    dst = (unsigned int*)(xq + (size_t)row * 1024);
    sp  = sx + row;
  } else {
    const int r = row - NTOK;
    src = w1 + (size_t)r * 1024;
    dst = (unsigned int*)(w1q + (size_t)r * 1024);
    sp  = sw + r;
  }
  const float4* s4 = (const float4*)src;
  float4 v[4];
  float m = 0.f;
#pragma unroll
  for (int j = 0; j < 4; ++j) {
    v[j] = s4[lane + 64 * j];
    m = fmaxf(m, fmaxf(fmaxf(fabsf(v[j].x), fabsf(v[j].y)),
                       fmaxf(fabsf(v[j].z), fabsf(v[j].w))));
  }
#pragma unroll
  for (int s = 1; s < 64; s <<= 1) m = fmaxf(m, __shfl_xor(m, s));
  m = fmaxf(m, 1e-20f);
  const float inv = 127.0f / m;
  if (lane == 0) *sp = m * (1.0f / 127.0f);
#pragma unroll
  for (int j = 0; j < 4; ++j) {
    const int a = (int)rintf(fminf(127.f, fmaxf(-127.f, v[j].x * inv)));
    const int b = (int)rintf(fminf(127.f, fmaxf(-127.f, v[j].y * inv)));
    const int c = (int)rintf(fminf(127.f, fmaxf(-127.f, v[j].z * inv)));
    const int d = (int)rintf(fminf(127.f, fmaxf(-127.f, v[j].w * inv)));
    dst[lane + 64 * j] = (unsigned)(a & 255) | ((unsigned)(b & 255) << 8) |
                         ((unsigned)(c & 255) << 16) | ((unsigned)(d & 255) << 24);
  }
}

static __device__ __forceinline__ void async16(const void* g, void* l) {
  __builtin_amdgcn_global_load_lds(
      (const __attribute__((address_space(1))) unsigned int*)g,
      (__attribute__((address_space(3))) unsigned int*)l, 16, 0, 0);
}

// Block: 128 tokens x 256 hcols (2 latents), 512 threads, 8 waves (wr=wave>>2, wc=wave&3).
// LDS main loop: A [0,16K) 128x128 i8 swz(r&7); B [16K,48K) 256x128 i8 swz(r&7).
// Epilogue (per latent round): h [0,32K) 128x128 bf16 swz(r&15); W2 [32K,48K).
__global__ __launch_bounds__(512, 4) void proto_fused(
    const signed char* __restrict__ xq,       // [8192][1024] i8
    const signed char* __restrict__ w1q,      // [16384][1024] i8
    const unsigned short* __restrict__ w2b,   // [128][64][128] bf16
    const float* __restrict__ sx,             // [8192]
    const float* __restrict__ sw,             // [16384]
    const float* __restrict__ b1,
    const float* __restrict__ gamma, const float* __restrict__ beta,
    const float* __restrict__ rmean, const float* __restrict__ rvar,
    const float* __restrict__ b2,
    const float* __restrict__ protos,
    float* __restrict__ out)                  // [8192][128]
{
  __shared__ __attribute__((aligned(128))) char smem[49152];
  const int tid  = threadIdx.x;
  const int wave = tid >> 6;
  const int lane = tid & 63;
  const int l15  = lane & 15;
  const int l4   = lane >> 4;
  const int wr   = wave >> 2;   // token half
  const int wc   = wave & 3;    // hcol quarter (64 cols)
  const int t0   = blockIdx.x * 128;
  const int lp   = blockIdx.y;  // latent pair

  // staging source maps (linear LDS dest chunk p -> swizzled global column)
  const signed char* srcA[2];
  const signed char* srcB[4];
  int dstA[2], dstB[4];
#pragma unroll
  for (int j = 0; j < 2; ++j) {
    const int p = j * 512 + tid;
    const int r = p >> 3;
    srcA[j] = xq + (size_t)(t0 + r) * NI + ((p & 7) ^ (r & 7)) * 16;
    dstA[j] = p * 16;
  }
#pragma unroll
  for (int j = 0; j < 4; ++j) {
    const int p = j * 512 + tid;
    const int r = p >> 3;
    srcB[j] = w1q + (size_t)(lp * 256 + r) * NI + ((p & 7) ^ (r & 7)) * 16;
    dstB[j] = 16384 + p * 16;
  }

  i32x4 acc[4][4] = {};

  auto stage = [&](int ks) {
    const int k0 = ks * 128;
#pragma unroll
    for (int j = 0; j < 2; ++j) async16(srcA[j] + k0, smem + dstA[j]);
#pragma unroll
    for (int j = 0; j < 4; ++j) async16(srcB[j] + k0, smem + dstB[j]);
  };

  int rbA[4], rbB[4];
#pragma unroll
  for (int m = 0; m < 4; ++m) rbA[m] = (wr * 64 + m * 16 + l15) * 128;
#pragma unroll
  for (int n = 0; n < 4; ++n) rbB[n] = 16384 + (wc * 64 + n * 16 + l15) * 128;
  const int rx = l15 & 7;

  // ---- GEMM1: i8, BK=128, 8 K-steps, single-buffered (m97 structure) ----
  stage(0);
  for (int ks = 0; ks < 8; ++ks) {
    __syncthreads();
#pragma unroll
    for (int kk = 0; kk < 2; ++kk) {
      const int koff = ((kk * 4 + l4) ^ rx) << 4;
      i32x4 a[4], b[4];
#pragma unroll
      for (int m = 0; m < 4; ++m) a[m] = *(const i32x4*)(smem + rbA[m] + koff);
#pragma unroll
      for (int n = 0; n < 4; ++n) b[n] = *(const i32x4*)(smem + rbB[n] + koff);
#pragma unroll
      for (int m = 0; m < 4; ++m)
#pragma unroll
        for (int n = 0; n < 4; ++n)
          acc[m][n] = __builtin_amdgcn_mfma_i32_16x16x64_i8(a[m], b[n], acc[m][n], 0, 0, 0);
    }
    __syncthreads();
    if (ks + 1 < 8) stage(ks + 1);
  }

  // ---- epilogue ----
  float sxv[4][4];
#pragma unroll
  for (int m = 0; m < 4; ++m)
#pragma unroll
    for (int r = 0; r < 4; ++r)
      sxv[m][r] = sx[t0 + wr * 64 + m * 16 + l4 * 4 + r];

  const int my_ep = wc >> 1;              // latent within pair this wave's cols belong to
  const int c0    = (wc & 1) * 64;
  const int lg_w  = lp * 2 + my_ep;

  // per-column folded constants: v = (acc*sxv)*K + C
  float Kc[4], Cc[4];
  int cch[4], cin[4];
#pragma unroll
  for (int n = 0; n < 4; ++n) {
    const int col = c0 + n * 16 + l15;
    const int gi  = lg_w * NH + col;
    const float sc_ = gamma[gi] * rsqrtf(rvar[gi] + 1e-5f);
    Kc[n] = sw[gi] * sc_;
    Cc[n] = b1[gi] * sc_ + beta[gi] - rmean[gi] * sc_;
    cch[n] = col >> 3;
    cin[n] = (col & 7) * 2;
  }

  const float act_scale = 300.0f / logf(10000.0f);

  for (int ep = 0; ep < 2; ++ep) {
    const int lg = lp * 2 + ep;
    if (my_ep == ep) {
      // dequant + BN + ReLU -> h bf16 [128][256B rows], chunk ^= row&15
#pragma unroll
      for (int n = 0; n < 4; ++n) {
#pragma unroll
        for (int m = 0; m < 4; ++m)
#pragma unroll
          for (int r = 0; r < 4; ++r) {
            float v = fmaf((float)acc[m][n][r] * sxv[m][r], Kc[n], Cc[n]);
            v = v > 0.f ? v : 0.f;
            const int row = wr * 64 + m * 16 + l4 * 4 + r;
            *(unsigned short*)(smem + row * 256 + ((cch[n] ^ (l4 * 4 + r)) << 4) + cin[n]) =
                f2bf(v);
          }
      }
    }
    // stage W2[lg]: 64x128 bf16 -> [32K,48K), chunk ^= row&15
#pragma unroll
    for (int j = 0; j < 2; ++j) {
      const int q = j * 512 + tid;
      const int r = q >> 4;
      const int c = (q & 15) ^ (r & 15);
      async16(w2b + (size_t)lg * NP * NH + r * NH + c * 8, smem + 32768 + q * 16);
    }
    __syncthreads();

    // GEMM2: enc = h @ W2^T (M=128, N=64, K=128); wave owns 16 token rows
    f32x4 acc2[4] = {};
    const int row2 = wave * 16 + l15;
#pragma unroll
    for (int kk = 0; kk < 4; ++kk) {
      const int kc = kk * 4 + l4;
      const bf16x8 a2 = *(const bf16x8*)(smem + row2 * 256 + ((kc ^ l15) << 4));
      bf16x8 bw[4];
#pragma unroll
      for (int n = 0; n < 4; ++n) {
        const int rp = n * 16 + l15;
        bw[n] = *(const bf16x8*)(smem + 32768 + rp * 256 + ((kc ^ l15) << 4));
      }
#pragma unroll
      for (int n = 0; n < 4; ++n)
        acc2[n] = __builtin_amdgcn_mfma_f32_16x16x32_bf16(a2, bw[n], acc2[n], 0, 0, 0);
    }

    // L2 distance + log activation
    float pb[4], pp[4];
#pragma unroll
    for (int n = 0; n < 4; ++n) {
      pb[n] = b2[lg * NP + n * 16 + l15];
      pp[n] = protos[lg * NP + n * 16 + l15];
    }
#pragma unroll
    for (int r = 0; r < 4; ++r) {
      float s = 0.f;
#pragma unroll
      for (int n = 0; n < 4; ++n) {
        const float e = acc2[n][r] + pb[n] - pp[n];
        s += e * e;
      }
      s += __shfl_xor(s, 1);
      s += __shfl_xor(s, 2);
      s += __shfl_xor(s, 4);
      s += __shfl_xor(s, 8);
      if (l15 == 0) {
        const float a = logf((s + 1.0f) / (s + 1e-4f)) * act_scale - 100.0f;
        out[(size_t)(t0 + wave * 16 + l4 * 4 + r) * NL + lg] = a;
      }
    }
    __syncthreads();   // GEMM2/h reads done before next round overwrites
  }
}

extern "C" void kernel_launch(void* const* d_in, const int* in_sizes, int n_in,
                              void* d_out, int out_size, void* d_ws, size_t ws_size,
                              hipStream_t stream) {
  const float* x      = (const float*)d_in[0];
  const float* W1     = (const float*)d_in[1];
  const float* b1     = (const float*)d_in[2];
  const float* gamma  = (const float*)d_in[3];
  const float* beta   = (const float*)d_in[4];
  const float* rmean  = (const float*)d_in[5];
  const float* rvar   = (const float*)d_in[6];
  const float* W2     = (const float*)d_in[7];
  const float* b2     = (const float*)d_in[8];
  const float* protos = (const float*)d_in[9];
  float* out = (float*)d_out;

  // workspace: xq 8MB | w1q 16MB | w2b 2MB | sx 32KB | sw 64KB
  char* ws = (char*)d_ws;
  signed char*    xq  = (signed char*)ws;
  signed char*    w1q = (signed char*)(ws + (size_t)8 * 1024 * 1024);
  unsigned short* w2b = (unsigned short*)(ws + (size_t)24 * 1024 * 1024);
  float*          sx  = (float*)(ws + (size_t)26 * 1024 * 1024);
  float*          sw  = (float*)(ws + (size_t)26 * 1024 * 1024 + 64 * 1024);

  quant_rows_i8_dual<<<(NTOK + NL * NH) / 4, 256, 0, stream>>>(x, W1, xq, w1q, sx, sw);
  {
    const int n8w2 = NL * NP * NH / 8;
    cvt_f32_bf16<<<(n8w2 + 255) / 256, 256, 0, stream>>>(W2, w2b, n8w2);
  }

  dim3 grid(NTOK / 128, NL / 2);
  proto_fused<<<grid, 512, 0, stream>>>(xq, w1q, w2b, sx, sw, b1, gamma, beta,
                                        rmean, rvar, b2, protos, out);
}

// Round 6
// 222.882 us; speedup vs baseline: 1.2422x; 1.2422x over previous
//
#include <hip/hip_runtime.h>

// ProtoSAE fused: h = relu(BN(x@W1^T + b1)); enc = h@W2^T + b2; act = f(||enc-proto||^2)
// T=8192, NI=1024, L=128, H=128, P=64.
// R6: revert to R4's proven geometry (128x128 tile, 4 waves, 48KB, 3 blocks/CU,
//     i8 GEMM1 BK=128). Epilogue cuts: folded BN constants, native bf16 casts,
//     log2-based activation. Merged quant prepass.

#define NTOK 8192
#define NI   1024
#define NL   128
#define NH   128
#define NP   64

typedef __bf16 bf16x8 __attribute__((ext_vector_type(8)));
typedef float f32x4 __attribute__((ext_vector_type(4)));
typedef int   i32x4 __attribute__((ext_vector_type(4)));

static __device__ __forceinline__ unsigned short f2bf(float f) {
  union { float f; unsigned int u; } v; v.f = f;
  const unsigned int u = v.u;
  return (unsigned short)((u + 0x7fffu + ((u >> 16) & 1u)) >> 16);  // RNE
}

// W2 -> bf16 (8 elems/thread)
__global__ void cvt_f32_bf16(const float* __restrict__ in,
                             unsigned short* __restrict__ out, int n8) {
  const int i = blockIdx.x * blockDim.x + threadIdx.x;
  if (i >= n8) return;
  const float4* p = (const float4*)in;
  const float4 a = p[2 * i], b = p[2 * i + 1];
  unsigned short v[8] __attribute__((aligned(16))) = {
      f2bf(a.x), f2bf(a.y), f2bf(a.z), f2bf(a.w),
      f2bf(b.x), f2bf(b.y), f2bf(b.z), f2bf(b.w)};
  ((uint4*)out)[i] = *(const uint4*)v;
}

// per-row symmetric int8 quantization of x (rows<NTOK) and W1 (rest); 1 wave per row
__global__ void quant_rows_i8_dual(const float* __restrict__ x,
                                   const float* __restrict__ w1,
                                   signed char* __restrict__ xq,
                                   signed char* __restrict__ w1q,
                                   float* __restrict__ sx,
                                   float* __restrict__ sw) {
  const int row = blockIdx.x * 4 + (threadIdx.x >> 6);
  const int lane = threadIdx.x & 63;
  const float* src;
  unsigned int* dst;
  float* sp;
  if (row < NTOK) {
    src = x + (size_t)row * 1024;
    dst = (unsigned int*)(xq + (size_t)row * 1024);
    sp  = sx + row;
  } else {
    const int r = row - NTOK;
    src = w1 + (size_t)r * 1024;
    dst = (unsigned int*)(w1q + (size_t)r * 1024);
    sp  = sw + r;
  }
  const float4* s4 = (const float4*)src;
  float4 v[4];
  float m = 0.f;
#pragma unroll
  for (int j = 0; j < 4; ++j) {
    v[j] = s4[lane + 64 * j];
    m = fmaxf(m, fmaxf(fmaxf(fabsf(v[j].x), fabsf(v[j].y)),
                       fmaxf(fabsf(v[j].z), fabsf(v[j].w))));
  }
#pragma unroll
  for (int s = 1; s < 64; s <<= 1) m = fmaxf(m, __shfl_xor(m, s));
  m = fmaxf(m, 1e-20f);
  const float inv = 127.0f / m;
  if (lane == 0) *sp = m * (1.0f / 127.0f);
#pragma unroll
  for (int j = 0; j < 4; ++j) {
    const int a = (int)rintf(fminf(127.f, fmaxf(-127.f, v[j].x * inv)));
    const int b = (int)rintf(fminf(127.f, fmaxf(-127.f, v[j].y * inv)));
    const int c = (int)rintf(fminf(127.f, fmaxf(-127.f, v[j].z * inv)));
    const int d = (int)rintf(fminf(127.f, fmaxf(-127.f, v[j].w * inv)));
    dst[lane + 64 * j] = (unsigned)(a & 255) | ((unsigned)(b & 255) << 8) |
                         ((unsigned)(c & 255) << 16) | ((unsigned)(d & 255) << 24);
  }
}

static __device__ __forceinline__ void async16(const void* g, void* l) {
  __builtin_amdgcn_global_load_lds(
      (const __attribute__((address_space(1))) unsigned int*)g,
      (__attribute__((address_space(3))) unsigned int*)l, 16, 0, 0);
}

// Block: 128 tokens x 1 latent, 4 waves as 2x2 (token-half x hcol-half).
// LDS: A [0,16K) 128x128 i8 swz(r&7); B [16K,32K) same; W2s [32K,48K) 64x128 bf16
//      swz(r&15) persistent; epilogue hs [0,32K) 128x128 bf16 swz(r&15).
__global__ __launch_bounds__(256, 3) void proto_fused(
    const signed char* __restrict__ xq,       // [8192][1024] i8
    const signed char* __restrict__ w1q,      // [16384][1024] i8
    const unsigned short* __restrict__ w2b,   // [128][64][128] bf16
    const float* __restrict__ sx,             // [8192]
    const float* __restrict__ sw,             // [16384]
    const float* __restrict__ b1,
    const float* __restrict__ gamma, const float* __restrict__ beta,
    const float* __restrict__ rmean, const float* __restrict__ rvar,
    const float* __restrict__ b2,
    const float* __restrict__ protos,
    float* __restrict__ out)                  // [8192][128]
{
  __shared__ __attribute__((aligned(128))) char smem[49152];
  const int tid  = threadIdx.x;
  const int wave = tid >> 6;
  const int lane = tid & 63;
  const int l15  = lane & 15;
  const int l4   = lane >> 4;
  const int wr   = wave >> 1;
  const int wc   = wave & 1;
  const int t0   = blockIdx.x * 128;
  const int lat  = blockIdx.y;

  const int srow  = lane >> 3;                    // row within 8-row staging chunk
  const int scolb = ((lane & 7) ^ srow) * 16;     // swizzled source byte offset

  i32x4 acc[4][4] = {};

  // ---- stage W2[lat] once: 64x128 bf16 -> smem+32768, chunk ^= row&15 swizzle ----
#pragma unroll
  for (int i = 0; i < 4; ++i) {
    const int r = wave * 4 + i * 16 + (lane >> 4);     // 0..63
    const int c = (lane & 15) ^ (r & 15);
    async16(w2b + (size_t)lat * NP * NH + r * NH + c * 8,
            smem + 32768 + (wave * 64 + i * 256) * 16);
  }

  auto stage = [&](int ks) {
    const int k0 = ks * 128;
#pragma unroll
    for (int j = 0; j < 4; ++j) {
      const int row = wave * 32 + j * 8 + srow;
      async16(xq + (size_t)(t0 + row) * NI + k0 + scolb,
              smem + (wave * 4 + j) * 1024);
      async16(w1q + (size_t)(lat * NH + row) * NI + k0 + scolb,
              smem + 16384 + (wave * 4 + j) * 1024);
    }
  };

  // ---- GEMM1 main loop: i8, BK=128, 8 K-steps, single-buffered (m97 structure) ----
  stage(0);
  const int rx = l15 & 7;
  for (int ks = 0; ks < 8; ++ks) {
    __syncthreads();
#pragma unroll
    for (int kk = 0; kk < 2; ++kk) {
      const int koff = ((kk * 4 + l4) ^ rx) << 4;
      i32x4 a[4], b[4];
#pragma unroll
      for (int m = 0; m < 4; ++m)
        a[m] = *(const i32x4*)(smem + (wr * 64 + m * 16 + l15) * 128 + koff);
#pragma unroll
      for (int n = 0; n < 4; ++n)
        b[n] = *(const i32x4*)(smem + 16384 + (wc * 64 + n * 16 + l15) * 128 + koff);
#pragma unroll
      for (int m = 0; m < 4; ++m)
#pragma unroll
        for (int n = 0; n < 4; ++n)
          acc[m][n] = __builtin_amdgcn_mfma_i32_16x16x64_i8(a[m], b[n], acc[m][n], 0, 0, 0);
    }
    __syncthreads();
    if (ks + 1 < 8) stage(ks + 1);
  }

  // ---- epilogue 1: dequant + BN(eval) + ReLU -> hs bf16 [128][128] swz(r&15) ----
  float sxv[4][4];
#pragma unroll
  for (int m = 0; m < 4; ++m)
#pragma unroll
    for (int r = 0; r < 4; ++r)
      sxv[m][r] = sx[t0 + wr * 64 + m * 16 + l4 * 4 + r];

#pragma unroll
  for (int n = 0; n < 4; ++n) {
    const int hc = wc * 64 + n * 16 + l15;
    const int gi = lat * NH + hc;
    const float sc_ = gamma[gi] * rsqrtf(rvar[gi] + 1e-5f);
    const float Kc  = sw[gi] * sc_;                                 // folded dequant*BN
    const float Cc  = b1[gi] * sc_ + beta[gi] - rmean[gi] * sc_;    // folded bias
    const int cchunk = hc >> 3, cin = (hc & 7) * 2;
#pragma unroll
    for (int m = 0; m < 4; ++m)
#pragma unroll
      for (int r = 0; r < 4; ++r) {
        float v = fmaf((float)acc[m][n][r] * sxv[m][r], Kc, Cc);
        v = v > 0.f ? v : 0.f;
        const int row = wr * 64 + m * 16 + l4 * 4 + r;
        const int pbyte = row * 256 + ((cchunk ^ (l4 * 4 + r)) << 4) + cin;
        *(__bf16*)(smem + pbyte) = (__bf16)v;     // native HW cvt
      }
  }
  __syncthreads();

  // ---- epilogue 2: enc = h @ W2^T (M=128, N=64, K=128), bf16, swizzled reads ----
  f32x4 acc2[2][4] = {};
#pragma unroll
  for (int kk = 0; kk < 4; ++kk) {
    const int pcsel = kk * 4 + l4;
    bf16x8 a2[2], bw[4];
#pragma unroll
    for (int m = 0; m < 2; ++m) {
      const int row = wave * 32 + m * 16 + l15;
      a2[m] = *(const bf16x8*)(smem + row * 256 + ((pcsel ^ (row & 15)) << 4));
    }
#pragma unroll
    for (int n = 0; n < 4; ++n) {
      const int rp = n * 16 + l15;
      bw[n] = *(const bf16x8*)(smem + 32768 + rp * 256 + ((pcsel ^ (rp & 15)) << 4));
    }
#pragma unroll
    for (int m = 0; m < 2; ++m)
#pragma unroll
      for (int n = 0; n < 4; ++n)
        acc2[m][n] = __builtin_amdgcn_mfma_f32_16x16x32_bf16(a2[m], bw[n], acc2[m][n], 0, 0, 0);
  }

  // ---- epilogue 3: L2 distance + log2-based activation ----
  float pb[4], pp[4];
#pragma unroll
  for (int n = 0; n < 4; ++n) {
    const int p = n * 16 + l15;
    pb[n] = b2[lat * NP + p];
    pp[n] = protos[lat * NP + p];
  }
  // act = (log2(s+1) - log2(s+1e-4)) * ln2 * 300/ln(1e4) - 100
  const float scale2 = 0.69314718056f * 300.0f / logf(10000.0f);
#pragma unroll
  for (int m = 0; m < 2; ++m)
#pragma unroll
    for (int r = 0; r < 4; ++r) {
      float s = 0.f;
#pragma unroll
      for (int n = 0; n < 4; ++n) {
        const float e = acc2[m][n][r] + pb[n] - pp[n];
        s += e * e;
      }
      s += __shfl_xor(s, 1);
      s += __shfl_xor(s, 2);
      s += __shfl_xor(s, 4);
      s += __shfl_xor(s, 8);
      if (l15 == 0) {
        const float a = (__log2f(s + 1.0f) - __log2f(s + 1e-4f)) * scale2 - 100.0f;
        const int trow = wave * 32 + m * 16 + l4 * 4 + r;
        out[(size_t)(t0 + trow) * NL + lat] = a;
      }
    }
}

extern "C" void kernel_launch(void* const* d_in, const int* in_sizes, int n_in,
                              void* d_out, int out_size, void* d_ws, size_t ws_size,
                              hipStream_t stream) {
  const float* x      = (const float*)d_in[0];
  const float* W1     = (const float*)d_in[1];
  const float* b1     = (const float*)d_in[2];
  const float* gamma  = (const float*)d_in[3];
  const float* beta   = (const float*)d_in[4];
  const float* rmean  = (const float*)d_in[5];
  const float* rvar   = (const float*)d_in[6];
  const float* W2     = (const float*)d_in[7];
  const float* b2     = (const float*)d_in[8];
  const float* protos = (const float*)d_in[9];
  float* out = (float*)d_out;

  // workspace: xq 8MB | w1q 16MB | w2b 2MB | sx 32KB | sw 64KB
  char* ws = (char*)d_ws;
  signed char*    xq  = (signed char*)ws;
  signed char*    w1q = (signed char*)(ws + (size_t)8 * 1024 * 1024);
  unsigned short* w2b = (unsigned short*)(ws + (size_t)24 * 1024 * 1024);
  float*          sx  = (float*)(ws + (size_t)26 * 1024 * 1024);
  float*          sw  = (float*)(ws + (size_t)26 * 1024 * 1024 + 64 * 1024);

  quant_rows_i8_dual<<<(NTOK + NL * NH) / 4, 256, 0, stream>>>(x, W1, xq, w1q, sx, sw);
  {
    const int n8w2 = NL * NP * NH / 8;
    cvt_f32_bf16<<<(n8w2 + 255) / 256, 256, 0, stream>>>(W2, w2b, n8w2);
  }

  dim3 grid(NTOK / 128, NL);
  proto_fused<<<grid, 256, 0, stream>>>(xq, w1q, w2b, sx, sw, b1, gamma, beta,
                                        rmean, rvar, b2, protos, out);
}